// Round 5
// baseline (447.960 us; speedup 1.0000x reference)
//
#include <hip/hip_runtime.h>
#include <stdint.h>

// FlowNetC correlation, bf16 MFMA banded-GEMM, v8.
// out[b, iy*21+ix, h, w] = (1/256) sum_c in1[b,c,h,w] * in2[b,c,h+dy,w+dx]
// Parity split w=2u+r, w'=2v+r, v=u+ix-10 -> banded Gram per (b, h-pair, r).
// ws layout (both inputs): [inp][b][h][row=r*48+u][c 256] bf16; in1 pre-scaled
// by 1/256 in pack (exact).
//
// v8 vs v7.1 (v7.1: occupancy 2x'd but dur ~same; per-block iteration latency
// invariant ~4800 cy across 4 structures -> serial-chain x resident-chains
// bound):
//  - __launch_bounds__(256,6): grid is exactly 6 blocks/CU; the old (256,4)
//    forced a 2nd scheduling round at 2/4 slots (the 32% occupancy plateau).
//    Now all 6 blocks co-resident (LDS 71KB/160KB, VGPR target <=85).
//  - Software-pipelined epilogue: after BAR, ISSUE the sO reads of iter i-1,
//    then run iter i's MFMAs (independent), then finish adds + nt-store.
//    Removes the in-order [BAR -> 120cy LDS read -> add -> store] chain from
//    the critical path. 2-buffer safety: reads of sO[ob(i-1)] complete before
//    this wave's lgkmcnt(0)+BAR of iter i; other waves' scatter into that
//    buffer happens only after that same barrier.

#define CP    256            // c row (512 B)
#define WSROW (96 * CP)      // 24576 bf16 = 49152 B per (input,b,h)

typedef __bf16 bf16x8 __attribute__((ext_vector_type(8)));
typedef float  f32x4  __attribute__((ext_vector_type(4)));

// ---------------- Phase 1: pack fp32 -> bf16, direct (no LDS)
// grid 1024 = [inp(2)][b(8)][h(64)], block 384 = x(96) x cig(4)
__global__ __launch_bounds__(384) void pack_kernel(
    const float* __restrict__ in1, const float* __restrict__ in2,
    __bf16* __restrict__ ws) {
  const int id = blockIdx.x;
  const float* src = (id >> 9) ? in2 : in1;
  const float scale = (id >> 9) ? 1.0f : 0.00390625f;   // in1 *= 1/256 (exact)
  const int bh = id & 511;
  const int b = bh >> 6, h = bh & 63;
  const int t = threadIdx.x;
  const int x = t >> 2, cig = t & 3;            // 4 lanes share one x
  const int row = (x & 1) * 48 + (x >> 1);      // parity-major row index

  const size_t sbase = (size_t)b * (256 * 64 * 96) + (size_t)h * 96 + x;
  __bf16* dst = ws + (size_t)id * WSROW + (size_t)row * CP;

#pragma unroll
  for (int g = 0; g < 8; ++g) {                 // c-chunks of 32
    const int cb = g * 32 + cig * 8;
    float v[8];
#pragma unroll
    for (int k = 0; k < 8; ++k)
      v[k] = src[sbase + (size_t)(cb + k) * (64 * 96)];
    bf16x8 o;
#pragma unroll
    for (int k = 0; k < 8; ++k) o[k] = (__bf16)(v[k] * scale);
    *(bf16x8*)(dst + cb) = o;                   // 4 lanes -> one full 64B line
  }
}

// ---------------- Phase 2: MFMA band-GEMM
// grid 1536 = [u0i(3)][h2(64)][b(8)], block 256 = 4 waves = (rr x kh)
__global__ __launch_bounds__(256, 6) void corr_mfma(
    const __bf16* __restrict__ ws, float* __restrict__ out) {
  const int gid = blockIdx.x;
  const int b = gid & 7;               // XCD affinity
  const int rest = gid >> 3;
  const int h2 = rest & 63;
  const int u0i = rest >> 6;           // 0..2
  const int u0 = u0i << 4;
  const int t = threadIdx.x;
  const int wv = t >> 6;
  const int rr = wv & 1;               // parity
  const int kh = wv >> 1;              // channel half: c in [128*kh, 128*kh+128)
  const int lane = t & 63;
  const int col = lane & 15, quad = lane >> 4;

  const __bf16* ws1 = ws;
  const __bf16* ws2 = ws + (size_t)512 * WSROW;

  __shared__ float sO[2][2][21][35];   // [buf][khalf][ix][w-local], stride 35

  // Zero both buffers once; out-of-band cells are i-invariant zeros.
  for (int idx = t; idx < 2 * 2 * 21 * 35; idx += 256) ((float*)sO)[idx] = 0.0f;

  // Zero-fill out rows whose in2 source row h2+dy is out of image.
  {
    const f32x4 z4 = {0.f, 0.f, 0.f, 0.f};
    for (int i = 0; i < 21; ++i) {
      int hh = h2 + 2 * i - 20;
      if (hh < 0 || hh >= 64) {
        float* obase = out + ((size_t)(b * 441 + i * 21) * 64 + h2) * 96 + 2 * u0;
        for (int idx = t; idx < 168; idx += 256) {
          int ix = idx >> 3, g = idx & 7;
          __builtin_nontemporal_store(
              z4, (f32x4*)(obase + (size_t)ix * 6144 + 4 * g));
        }
      }
    }
  }

  const int i_lo = max(0, (h2 - 42) >> 1);
  const int i_hi = min(20, (h2 + 20) >> 1);

  __syncthreads();                     // sO init visible before first scatter

  // Band tiles this u0 needs (edge blocks drop their all-zero tile).
  const int tl = (u0i == 0) ? 1 : 0;
  const int th = (u0i == 2) ? 1 : 2;

  // B fragments -> registers (once), this wave's K-half only.
  bf16x8 bfrag[3][4];
  {
    const __bf16* brow = ws2 + (size_t)(b * 64 + h2) * WSROW;
#pragma unroll
    for (int tt = 0; tt < 3; ++tt) {
      if (tt < tl || tt > th) continue;          // uniform branch
      const int v = u0 + 16 * (tt - 1) + col;
      const __bf16* p = brow + (size_t)(rr * 48 + v) * CP + kh * 128 + quad * 8;
#pragma unroll
      for (int sl = 0; sl < 4; ++sl)
        bfrag[tt][sl] = *(const bf16x8*)(p + 32 * sl);
    }
  }

  const int aoff = (rr * 48 + u0 + col) * CP + kh * 128 + quad * 8;

  auto loadA = [&](bf16x8(&a)[4], int i) {
    const __bf16* p = ws1 + (size_t)(b * 64 + (h2 - 2 * i + 20)) * WSROW + aoff;
#pragma unroll
    for (int sl = 0; sl < 4; ++sl) a[sl] = *(const bf16x8*)(p + 32 * sl);
  };

  auto mfma3 = [&](const bf16x8(&a)[4], f32x4(&acc)[3]) {
#pragma unroll
    for (int tt = 0; tt < 3; ++tt) acc[tt] = (f32x4){0.f, 0.f, 0.f, 0.f};
#pragma unroll
    for (int tt = 0; tt < 3; ++tt) {
      if (tt < tl || tt > th) continue;
#pragma unroll
      for (int sl = 0; sl < 4; ++sl)
        acc[tt] = __builtin_amdgcn_mfma_f32_16x16x32_bf16(a[sl], bfrag[tt][sl],
                                                          acc[tt], 0, 0, 0);
    }
  };

  auto scatter = [&](const f32x4(&acc)[3], int ob) {
#pragma unroll
    for (int tt = 0; tt < 3; ++tt) {
      if (tt < tl || tt > th) continue;
#pragma unroll
      for (int reg = 0; reg < 4; ++reg) {
        int du = quad * 4 + reg;
        int ix = (tt - 1) * 16 + col - du + 10;
        if (ix >= 0 && ix < 21)
          sO[ob][kh][ix][2 * du + rr] = acc[tt][reg];
      }
    }
  };

  // Pipelined epilogue: issue reads early, finish (adds + nt-store) late.
  const int eIx = t >> 3, eG = t & 7;          // t < 168 active
  const bool eAct = (t < 168);

  auto epi_read = [&](int ob, float(&e)[8]) {
    if (eAct) {
#pragma unroll
      for (int k = 0; k < 4; ++k) {
        e[k]     = sO[ob][0][eIx][4 * eG + k];
        e[4 + k] = sO[ob][1][eIx][4 * eG + k];
      }
    }
  };
  auto epi_finish = [&](int i, const float(&e)[8]) {
    if (eAct) {
      f32x4 v;
      v.x = e[0] + e[4];
      v.y = e[1] + e[5];
      v.z = e[2] + e[6];
      v.w = e[3] + e[7];
      const int h = h2 - 2 * i + 20;
      float* obase = out + ((size_t)(b * 441 + i * 21) * 64 + h) * 96 + 2 * u0;
      __builtin_nontemporal_store(
          v, (f32x4*)(obase + (size_t)eIx * 6144 + 4 * eG));
    }
  };

  auto bar = [&]() {
    asm volatile("s_waitcnt lgkmcnt(0)" ::: "memory");
    __builtin_amdgcn_sched_barrier(0);
    __builtin_amdgcn_s_barrier();
    __builtin_amdgcn_sched_barrier(0);
  };

  // ---- main pipeline. Buffer of iteration i is (i - i_lo) & 1.
  bf16x8 aX[4], aY[4];
  float e[8];

  loadA(aX, i_lo);
  if (i_lo < i_hi) loadA(aY, i_lo + 1);
  {
    f32x4 acc[3];
    mfma3(aX, acc);
    scatter(acc, 0);
  }
  bar();

  for (int i = i_lo + 1; i <= i_hi; ++i) {
    const int par = (i - i_lo) & 1;            // block-uniform branch
    epi_read(par ^ 1, e);                      // issue reads of iter i-1
    if (par) {
      if (i < i_hi) loadA(aX, i + 1);
      f32x4 acc[3];
      mfma3(aY, acc);                          // hides the LDS read latency
      epi_finish(i - 1, e);
      scatter(acc, par);
    } else {
      if (i < i_hi) loadA(aY, i + 1);
      f32x4 acc[3];
      mfma3(aX, acc);
      epi_finish(i - 1, e);
      scatter(acc, par);
    }
    bar();
  }

  // drain last epilogue
  epi_read((i_hi - i_lo) & 1, e);
  epi_finish(i_hi, e);
}

extern "C" void kernel_launch(void* const* d_in, const int* in_sizes, int n_in,
                              void* d_out, int out_size, void* d_ws, size_t ws_size,
                              hipStream_t stream) {
  const float* in1 = (const float*)d_in[0];
  const float* in2 = (const float*)d_in[1];
  float* out = (float*)d_out;
  __bf16* ws = (__bf16*)d_ws;    // 1024 * 24576 bf16 = 50.3 MB

  pack_kernel<<<1024, 384, 0, stream>>>(in1, in2, ws);
  corr_mfma<<<1536, 256, 0, stream>>>(ws, out);
}

// Round 6
// 319.522 us; speedup vs baseline: 1.4020x; 1.4020x over previous
//
#include <hip/hip_runtime.h>
#include <stdint.h>

// FlowNetC correlation, bf16 MFMA banded-GEMM, v9.
// out[b, iy*21+ix, h, w] = (1/256) sum_c in1[b,c,h,w] * in2[b,c,h+dy,w+dx]
// Parity split w=2u+r, w'=2v+r, v=u+ix-10 -> banded Gram per (b, h-pair, r).
// ws layout (both inputs): [inp][b][h][row=r*48+u][c 256] bf16; in1 pre-scaled
// by 1/256 in pack (exact).
//
// v9 vs v7.1/v8: four prior structures all pinned at 71-80us with every pipe
// <10% busy -- the invariant was the per-iteration workgroup barrier used to
// assemble the [21][32] output tile in LDS (cross-wave parity/K interleave).
// v8's (256,6) bound also proved launch_bounds arg2 is a REGISTER hint, not a
// residency cap (40 VGPRs -> spill -> 663MB scratch fetch).
// New partition: 6 waves/block = (band-tile tt 0..2) x (parity rr). Each
// (u,v) Gram cell belongs to exactly one tt, so each wave's accumulator cells
// are DISJOINT output elements -> predicated dword stores straight to global
// (normal stores; L2 assembles full lines from the block's co-resident
// waves). No LDS, no barriers, no epilogue. K=256/wave, two independent
// 4-deep MFMA chains. Edge waves (tile fully outside image) exit early.

#define CP    256            // c row (512 B)
#define WSROW (96 * CP)      // 24576 bf16 = 49152 B per (input,b,h)

typedef __bf16 bf16x8 __attribute__((ext_vector_type(8)));
typedef float  f32x4  __attribute__((ext_vector_type(4)));

// ---------------- Phase 1: pack fp32 -> bf16, direct (no LDS)
// grid 1024 = [inp(2)][b(8)][h(64)], block 384 = x(96) x cig(4)
__global__ __launch_bounds__(384) void pack_kernel(
    const float* __restrict__ in1, const float* __restrict__ in2,
    __bf16* __restrict__ ws) {
  const int id = blockIdx.x;
  const float* src = (id >> 9) ? in2 : in1;
  const float scale = (id >> 9) ? 1.0f : 0.00390625f;   // in1 *= 1/256 (exact)
  const int bh = id & 511;
  const int b = bh >> 6, h = bh & 63;
  const int t = threadIdx.x;
  const int x = t >> 2, cig = t & 3;            // 4 lanes share one x
  const int row = (x & 1) * 48 + (x >> 1);      // parity-major row index

  const size_t sbase = (size_t)b * (256 * 64 * 96) + (size_t)h * 96 + x;
  __bf16* dst = ws + (size_t)id * WSROW + (size_t)row * CP;

#pragma unroll
  for (int g = 0; g < 8; ++g) {                 // c-chunks of 32
    const int cb = g * 32 + cig * 8;
    float v[8];
#pragma unroll
    for (int k = 0; k < 8; ++k)
      v[k] = src[sbase + (size_t)(cb + k) * (64 * 96)];
    bf16x8 o;
#pragma unroll
    for (int k = 0; k < 8; ++k) o[k] = (__bf16)(v[k] * scale);
    *(bf16x8*)(dst + cb) = o;                   // 4 lanes -> one full 64B line
  }
}

// ---------------- Phase 2: MFMA band-GEMM, barrier-free
// grid 1536 = [u0i(3)][h2(64)][b(8)], block 384 = 6 waves = (tt x rr)
__global__ __launch_bounds__(384, 3) void corr_mfma(
    const __bf16* __restrict__ ws, float* __restrict__ out) {
  const int gid = blockIdx.x;
  const int b = gid & 7;               // XCD affinity (blockIdx%8 -> XCD)
  const int rest = gid >> 3;
  const int h2 = rest & 63;            // in2 row this block correlates against
  const int u0i = rest >> 6;           // 0..2 : u-tile (w-slice [32*u0i, +32))
  const int u0 = u0i << 4;
  const int t = threadIdx.x;
  const int wv = t >> 6;               // 0..5
  const int rr = wv & 1;               // parity
  const int tt = wv >> 1;              // band tile: v in [u0+16(tt-1), +16)
  const int lane = t & 63;
  const int col = lane & 15, quad = lane >> 4;

  // Zero-fill output rows (out-row = h2) whose in2 source row is invalid.
  // Full 64B lines via f32x4 nt stores; no sync needed (disjoint from compute).
  if (t < 168) {
    const f32x4 z4 = {0.f, 0.f, 0.f, 0.f};
    const int zix = t >> 3, zg = t & 7;
    for (int i = 0; i < 21; ++i) {
      int hh = h2 + 2 * i - 20;
      if (hh < 0 || hh >= 64) {
        float* p = out + ((size_t)(b * 441 + i * 21 + zix) * 64 + h2) * 96
                   + 2 * u0 + 4 * zg;
        __builtin_nontemporal_store(z4, (f32x4*)p);
      }
    }
  }

  // Edge waves: band tile entirely outside the image (v<0 or v>=48).
  if ((u0i == 0 && tt == 0) || (u0i == 2 && tt == 2)) return;

  const __bf16* ws1 = ws;
  const __bf16* ws2 = ws + (size_t)512 * WSROW;

  // B fragments -> registers, once. v in [0,48) for surviving waves.
  bf16x8 bfrag[8];
  {
    const int v = u0 + 16 * (tt - 1) + col;
    const __bf16* p = ws2 + (size_t)(b * 64 + h2) * WSROW
                      + (size_t)(rr * 48 + v) * CP + quad * 8;
#pragma unroll
    for (int s = 0; s < 8; ++s) bfrag[s] = *(const bf16x8*)(p + 32 * s);
  }

  // Per-lane store offsets + predicates (i-invariant).
  // D row = u-off = quad*4+reg, D col = v-off = col; ix = v-u+10.
  int soff[4];
  bool sval[4];
#pragma unroll
  for (int reg = 0; reg < 4; ++reg) {
    const int du = quad * 4 + reg;
    const int ix = (tt - 1) * 16 + col - du + 10;
    sval[reg] = (ix >= 0 && ix < 21);
    soff[reg] = ix * 6144 + 2 * (u0 + du) + rr;
  }

  const int i_lo = max(0, (h2 - 42) >> 1);
  const int i_hi = min(20, (h2 + 20) >> 1);

  const int aoff = (rr * 48 + u0 + col) * CP + quad * 8;

  auto loadA = [&](bf16x8(&a)[8], int i) {
    const __bf16* p = ws1 + (size_t)(b * 64 + (h2 - 2 * i + 20)) * WSROW + aoff;
#pragma unroll
    for (int s = 0; s < 8; ++s) a[s] = *(const bf16x8*)(p + 32 * s);
  };

  auto body = [&](const bf16x8(&a)[8], int i) {
    f32x4 accA = {0.f, 0.f, 0.f, 0.f};
    f32x4 accB = {0.f, 0.f, 0.f, 0.f};
#pragma unroll
    for (int s = 0; s < 4; ++s) {      // two independent 4-deep chains
      accA = __builtin_amdgcn_mfma_f32_16x16x32_bf16(a[s],     bfrag[s],
                                                     accA, 0, 0, 0);
      accB = __builtin_amdgcn_mfma_f32_16x16x32_bf16(a[s + 4], bfrag[s + 4],
                                                     accB, 0, 0, 0);
    }
    const f32x4 acc = accA + accB;
    const int h = h2 - 2 * i + 20;
    float* base = out + (size_t)(b * 441 + i * 21) * 6144 + h * 96;
#pragma unroll
    for (int reg = 0; reg < 4; ++reg)
      if (sval[reg]) base[soff[reg]] = acc[reg];   // L2 assembles lines
  };

  // Software-pipelined, barrier-free main loop (prefetch distance 1).
  bf16x8 a0[8], a1[8];
  int i = i_lo;
  loadA(a0, i);
  __builtin_amdgcn_sched_barrier(0);
  while (i + 1 <= i_hi) {
    loadA(a1, i + 1);
    __builtin_amdgcn_sched_barrier(0);
    body(a0, i);
    if (i + 2 <= i_hi) {
      loadA(a0, i + 2);
      __builtin_amdgcn_sched_barrier(0);
    }
    body(a1, i + 1);
    i += 2;
  }
  if (i <= i_hi) body(a0, i);
}

extern "C" void kernel_launch(void* const* d_in, const int* in_sizes, int n_in,
                              void* d_out, int out_size, void* d_ws, size_t ws_size,
                              hipStream_t stream) {
  const float* in1 = (const float*)d_in[0];
  const float* in2 = (const float*)d_in[1];
  float* out = (float*)d_out;
  __bf16* ws = (__bf16*)d_ws;    // 1024 * 24576 bf16 = 50.3 MB

  pack_kernel<<<1024, 384, 0, stream>>>(in1, in2, ws);
  corr_mfma<<<1536, 384, 0, stream>>>(ws, out);
}